// Round 8
// baseline (58.926 us; speedup 1.0000x reference)
//
#include <hip/hip_runtime.h>
#include <cmath>

#define THREADS 256
#define NCELL 10
#define DDIM 9

typedef float f32x2 __attribute__((ext_vector_type(2)));

__device__ __forceinline__ f32x2 fma2(f32x2 a, f32x2 b, f32x2 c) {
  return __builtin_elementwise_fma(a, b, c);   // v_pk_fma_f32 on gfx950
}
__device__ __forceinline__ f32x2 max2(f32x2 a, f32x2 b) {
  return __builtin_elementwise_max(a, b);      // v_pk_max_f32
}

struct Basis { float Bt[DDIM][2 * NCELL]; }; // Bt[t][l] = B[l][t]

// Reproduce numpy.linalg.svd(L) Vt[11:] rows: LAPACK dgesdd Path 4t leaves
// rows m..n-1 of VT equal to the LQ-factorization orthogonal complement
// (dgelqf + dorglq). Replicate dlarfg/dgelq2/dorgl2 in double precision.
static void compute_basis_host(Basis* bs) {
  double L[11][20];
  for (int r = 0; r < 11; ++r)
    for (int c = 0; c < 20; ++c) L[r][c] = 0.0;
  for (int k = 1; k < NCELL; ++k) {
    double xk = (double)k / (double)NCELL;
    L[k - 1][2 * (k - 1)] = xk;
    L[k - 1][2 * (k - 1) + 1] = 1.0;
    L[k - 1][2 * k] = -xk;
    L[k - 1][2 * k + 1] = -1.0;
  }
  L[NCELL - 1][1] = 1.0;
  L[NCELL][2 * (NCELL - 1)] = 1.0;
  L[NCELL][2 * (NCELL - 1) + 1] = 1.0;

  double v[11][20];
  double tau[11];
  for (int i = 0; i < 11; ++i) {
    double alpha = L[i][i];
    double xn2 = 0.0;
    for (int l = i + 1; l < 20; ++l) xn2 += L[i][l] * L[i][l];
    double xnorm = sqrt(xn2);
    for (int l = 0; l < 20; ++l) v[i][l] = 0.0;
    v[i][i] = 1.0;
    if (xnorm == 0.0) {
      tau[i] = 0.0;
    } else {
      double beta = sqrt(alpha * alpha + xn2);
      if (alpha >= 0.0) beta = -beta;        // dlarfg: beta = -sign(alpha)*norm
      tau[i] = (beta - alpha) / beta;
      double sc = 1.0 / (alpha - beta);
      for (int l = i + 1; l < 20; ++l) v[i][l] = L[i][l] * sc;
      L[i][i] = beta;
      for (int j = i + 1; j < 11; ++j) {
        double w = 0.0;
        for (int l = i; l < 20; ++l) w += L[j][l] * v[i][l];
        w *= tau[i];
        for (int l = i; l < 20; ++l) L[j][l] -= w * v[i][l];
      }
    }
  }
  for (int j = 11; j < 20; ++j) {
    double q[20];
    for (int l = 0; l < 20; ++l) q[l] = 0.0;
    q[j] = 1.0;
    for (int i = 10; i >= 0; --i) {
      double w = 0.0;
      for (int l = i; l < 20; ++l) w += v[i][l] * q[l];
      w *= tau[i];
      for (int l = i; l < 20; ++l) q[l] -= w * v[i][l];
    }
    for (int l = 0; l < 20; ++l) bs->Bt[j - 11][l] = (float)q[l];
  }
}

// Fold W3B[r][l] = sum_t w3[r*9+t]*Bt[t][l] (10x20) and b3B[l] = sum_t b3[t]*Bt[t][l]
// per MLP into ws: [m1: 200 W + 20 b][m2: 200 W + 20 b] floats.
__global__ void fold_kernel(const float* __restrict__ w3_1, const float* __restrict__ b3_1,
                            const float* __restrict__ w3_2, const float* __restrict__ b3_2,
                            float* __restrict__ ws, Basis bb) {
  for (int f = threadIdx.x; f < 440; f += THREADS) {
    int m = f / 220;
    int j = f % 220;
    const float* w3 = (m == 0) ? w3_1 : w3_2;
    const float* b3 = (m == 0) ? b3_1 : b3_2;
    float val = 0.0f;
    if (j < 200) {
      int r = j / 20, l = j % 20;
      for (int t = 0; t < DDIM; ++t) val += w3[r * DDIM + t] * bb.Bt[t][l];
    } else {
      int l = j - 200;
      for (int t = 0; t < DDIM; ++t) val += b3[t] * bb.Bt[t][l];
    }
    ws[f] = val;
  }
}

// MLP (1->10->10->10) then A = h2 @ W3B + b3B written to this thread's LDS column.
__device__ __forceinline__ void mlp_A(float xin,
    const float* __restrict__ w0, const float* __restrict__ b0,
    const float* __restrict__ w1, const float* __restrict__ b1,
    const float* __restrict__ w2, const float* __restrict__ b2,
    const float* __restrict__ wbf,     // 220 floats: 100 f32x2 W3B pairs + 10 f32x2 b3B pairs
    f32x2* abcol) {
  const f32x2* w0p = (const f32x2*)w0;
  const f32x2* b0p = (const f32x2*)b0;
  const f32x2* w1p = (const f32x2*)w1;
  const f32x2* b1p = (const f32x2*)b1;
  const f32x2* w2p = (const f32x2*)w2;
  const f32x2* b2p = (const f32x2*)b2;
  const f32x2* WB  = (const f32x2*)wbf;

  f32x2 h0[5], h1[5], h2[5];
  f32x2 xx = {xin, xin};
#pragma unroll
  for (int p = 0; p < 5; ++p) h0[p] = fma2(xx, w0p[p], b0p[p]);

#pragma unroll
  for (int p = 0; p < 5; ++p) h1[p] = b1p[p];
#pragma unroll
  for (int r = 0; r < 10; ++r) {
    float h = h0[r >> 1][r & 1];
    f32x2 hh = {h, h};
#pragma unroll
    for (int p = 0; p < 5; ++p) h1[p] = fma2(hh, w1p[r * 5 + p], h1[p]);
  }
  f32x2 zero = {0.0f, 0.0f};
#pragma unroll
  for (int p = 0; p < 5; ++p) h1[p] = max2(h1[p], zero);

#pragma unroll
  for (int p = 0; p < 5; ++p) h2[p] = b2p[p];
#pragma unroll
  for (int r = 0; r < 10; ++r) {
    float h = h1[r >> 1][r & 1];
    f32x2 hh = {h, h};
#pragma unroll
    for (int p = 0; p < 5; ++p) h2[p] = fma2(hh, w2p[r * 5 + p], h2[p]);
  }
#pragma unroll
  for (int p = 0; p < 5; ++p) h2[p] = max2(h2[p], zero);

  f32x2 acc[NCELL];
#pragma unroll
  for (int l = 0; l < NCELL; ++l) acc[l] = WB[100 + l];   // b3B pairs
#pragma unroll
  for (int r = 0; r < 10; ++r) {
    float h = h2[r >> 1][r & 1];
    f32x2 hh = {h, h};
#pragma unroll
    for (int l = 0; l < NCELL; ++l) acc[l] = fma2(hh, WB[r * 10 + l], acc[l]);
  }
#pragma unroll
  for (int l = 0; l < NCELL; ++l) abcol[l * THREADS] = acc[l];
}

// One cell-hop step, trans-minimized (r7 body): exp/evolve deferred post-loop,
// ld accumulates the log-ratio directly on crossings, frozen (edge ping-pong)
// lanes counted as done for the early-exit vote.
__device__ __forceinline__ void flow_it(const f32x2* col, float& phi, float& t,
                                        float& ld, float& trem, int& c,
                                        bool& lin_any, bool& stop) {
  f32x2 ab = col[c * THREADS];
  float a = ab[0], b = ab[1];
  float v = fmaf(a, phi, b);
  float rv = __builtin_amdgcn_rcpf(v);
  bool right = (v >= 0.0f);
  int xci = right ? (c + 1) : c;
  float xc = (float)xci * 0.1f;
  int cn = right ? (c + 1) : (c - 1);
  cn = cn < 0 ? 0 : (cn > 9 ? 9 : cn);
  float vxc = fmaf(a, xc, b);
  float ratio = fmaxf(vxc * rv, 1e-30f);
  float l = __logf(ratio);                     // v_log_f32
  bool lin = fabsf(a) < 1e-10f;
  lin_any = lin;
  float sa = lin ? 1.0f : a;
  float thit = l * __builtin_amdgcn_rcpf(sa);
  if (lin) {                                   // ~never; per-lane fixup
    float sb = (fabsf(b) < 1e-30f) ? 1.0f : b;
    thit = (xc - phi) * __builtin_amdgcn_rcpf(sb);
  }
  thit = (fabsf(v) < 1e-14f) ? __builtin_inff() : thit;
  bool active = t > 0.0f;
  bool cross = thit < t;
  bool ac = active && cross;
  bool term = active && !cross;
  bool frozen = ac && (xc == phi) && (cn == c);  // exact no-op crossing
  trem = term ? t : trem;
  ld += ac ? l : 0.0f;
  phi = ac ? xc : phi;
  t = active ? (cross ? (t - thit) : 0.0f) : t;
  c = ac ? cn : c;
  stop = (t <= 0.0f) || frozen;
}

// Post-loop: evolve once inside the terminal cell (reference formulas).
__device__ __forceinline__ void flow_fin(const f32x2* col, float phi, float trem,
                                         float ld, int c, float& zo, float& ldo) {
  f32x2 abf = col[c * THREADS];
  float aF = abf[0], bF = abf[1];
  bool done = trem > 0.0f;
  bool linf = fabsf(aF) < 1e-10f;
  float rsaf = __builtin_amdgcn_rcpf(linf ? 1.0f : aF);
  float bsa = bF * rsaf;
  float E = __expf(aF * trem);                 // the ONLY exp in the flow
  float pnl = fmaf(phi + bsa, E, -bsa);
  float pli = fmaf(bF, trem, phi);
  float p1 = linf ? pli : pnl;
  zo = done ? p1 : phi;
  ldo = ld + (done ? aF * trem : 0.0f);
}

// Two independent flows fused in one loop: 2x ILP fills the issue bubbles the
// single-chain version leaves (r3/r5/r7 all pinned at ~56us, VALUBusy ~75%).
__device__ __forceinline__ void flow2(float x0A, const f32x2* colA,
                                      float x0B, const f32x2* colB,
                                      float& zA, float& ldA,
                                      float& zB, float& ldB) {
  float phiA = x0A, tA = 1.0f, lA = 0.0f, trA = 0.0f;
  float phiB = x0B, tB = 1.0f, lB = 0.0f, trB = 0.0f;
  int cA = (int)(x0A * 10.0f); cA = cA < 0 ? 0 : (cA > 9 ? 9 : cA);
  int cB = (int)(x0B * 10.0f); cB = cB < 0 ? 0 : (cB > 9 ? 9 : cB);
  for (int it = 0; it < NCELL; ++it) {
    bool linA, linB, stopA, stopB;
    flow_it(colA, phiA, tA, lA, trA, cA, linA, stopA);
    flow_it(colB, phiB, tB, lB, trB, cB, linB, stopB);
    if (__all(stopA && stopB)) break;
  }
  flow_fin(colA, phiA, trA, lA, cA, zA, ldA);
  flow_fin(colB, phiB, trB, lB, cB, zB, ldB);
}

__global__ __launch_bounds__(THREADS, 4) void cpab2d_kernel(
    const float* __restrict__ x,
    const float* __restrict__ m1w0, const float* __restrict__ m1b0,
    const float* __restrict__ m1w1, const float* __restrict__ m1b1,
    const float* __restrict__ m1w2, const float* __restrict__ m1b2,
    const float* __restrict__ m2w0, const float* __restrict__ m2b0,
    const float* __restrict__ m2w1, const float* __restrict__ m2b1,
    const float* __restrict__ m2w2, const float* __restrict__ m2b2,
    const float* __restrict__ wsf,
    float* __restrict__ out, int n) {
  __shared__ f32x2 AB[2][NCELL][THREADS];  // f32 (a,b); [elem][cell][tid]
  int tid = threadIdx.x;
  int i0 = blockIdx.x * (2 * THREADS) + tid;
  int i1 = i0 + THREADS;
  bool p0 = i0 < n, p1 = i1 < n;

  float2 xi0 = p0 ? reinterpret_cast<const float2*>(x)[i0] : make_float2(0.5f, 0.5f);
  float2 xi1 = p1 ? reinterpret_cast<const float2*>(x)[i1] : make_float2(0.5f, 0.5f);
  // xs = x[:, [1,0]]: x1 = x[:,1], x2 = x[:,0]; both clipped first
  float x2a = fminf(fmaxf(xi0.x, 1e-7f), 1.0f - 1e-7f);
  float x1a = fminf(fmaxf(xi0.y, 1e-7f), 1.0f - 1e-7f);
  float x2b = fminf(fmaxf(xi1.x, 1e-7f), 1.0f - 1e-7f);
  float x1b = fminf(fmaxf(xi1.y, 1e-7f), 1.0f - 1e-7f);

  f32x2* colA = &AB[0][0][tid];
  f32x2* colB = &AB[1][0][tid];

  // theta2 = mlp(x1, m2); z2,g2 = flow(x2, theta2)  -- two independent chains
  mlp_A(x1a, m2w0, m2b0, m2w1, m2b1, m2w2, m2b2, wsf + 220, colA);
  mlp_A(x1b, m2w0, m2b0, m2w1, m2b1, m2w2, m2b2, wsf + 220, colB);
  float z2a, l2a, z2b, l2b;
  flow2(x2a, colA, x2b, colB, z2a, l2a, z2b, l2b);

  // theta1 = mlp(z2, m1); z1,g1 = flow(x1, theta1)
  mlp_A(z2a, m1w0, m1b0, m1w1, m1b1, m1w2, m1b2, wsf, colA);
  mlp_A(z2b, m1w0, m1b0, m1w1, m1b1, m1w2, m1b2, wsf, colB);
  float z1a, l1a, z1b, l1b;
  flow2(x1a, colA, x1b, colB, z1a, l1a, z1b, l1b);

  // z = [z2, z1]; log_dz_dx = [ld2, ld1]
  float2* oz = reinterpret_cast<float2*>(out);
  float2* ol = reinterpret_cast<float2*>(out + 2 * (size_t)n);
  if (p0) { oz[i0] = make_float2(z2a, z1a); ol[i0] = make_float2(l2a, l1a); }
  if (p1) { oz[i1] = make_float2(z2b, z1b); ol[i1] = make_float2(l2b, l1b); }
}

extern "C" void kernel_launch(void* const* d_in, const int* in_sizes, int n_in,
                              void* d_out, int out_size, void* d_ws, size_t ws_size,
                              hipStream_t stream) {
  const float* x    = (const float*)d_in[0];
  const float* m1w0 = (const float*)d_in[1];
  const float* m1b0 = (const float*)d_in[2];
  const float* m1w1 = (const float*)d_in[3];
  const float* m1b1 = (const float*)d_in[4];
  const float* m1w2 = (const float*)d_in[5];
  const float* m1b2 = (const float*)d_in[6];
  const float* m1w3 = (const float*)d_in[7];
  const float* m1b3 = (const float*)d_in[8];
  const float* m2w0 = (const float*)d_in[9];
  const float* m2b0 = (const float*)d_in[10];
  const float* m2w1 = (const float*)d_in[11];
  const float* m2b1 = (const float*)d_in[12];
  const float* m2w2 = (const float*)d_in[13];
  const float* m2b2 = (const float*)d_in[14];
  const float* m2w3 = (const float*)d_in[15];
  const float* m2b3 = (const float*)d_in[16];
  float* out = (float*)d_out;
  float* wsf = (float*)d_ws;
  int n = in_sizes[0] / 2;

  Basis bs;
  compute_basis_host(&bs);

  fold_kernel<<<1, THREADS, 0, stream>>>(m1w3, m1b3, m2w3, m2b3, wsf, bs);

  int per_block = 2 * THREADS;
  dim3 grid((n + per_block - 1) / per_block), block(THREADS);
  cpab2d_kernel<<<grid, block, 0, stream>>>(
      x, m1w0, m1b0, m1w1, m1b1, m1w2, m1b2,
      m2w0, m2b0, m2w1, m2b1, m2w2, m2b2,
      wsf, out, n);
}

// Round 9
// 56.777 us; speedup vs baseline: 1.0379x; 1.0379x over previous
//
#include <hip/hip_runtime.h>
#include <cmath>

#define THREADS 256
#define NCELL 10
#define DDIM 9

typedef float f32x2 __attribute__((ext_vector_type(2)));

__device__ __forceinline__ f32x2 fma2(f32x2 a, f32x2 b, f32x2 c) {
  return __builtin_elementwise_fma(a, b, c);   // v_pk_fma_f32 on gfx950
}
__device__ __forceinline__ f32x2 max2(f32x2 a, f32x2 b) {
  return __builtin_elementwise_max(a, b);      // v_pk_max_f32
}

struct Basis { float Bt[DDIM][2 * NCELL]; }; // Bt[t][l] = B[l][t]

// Reproduce numpy.linalg.svd(L) Vt[11:] rows: LAPACK dgesdd Path 4t leaves
// rows m..n-1 of VT equal to the LQ-factorization orthogonal complement
// (dgelqf + dorglq). Replicate dlarfg/dgelq2/dorgl2 in double precision.
static void compute_basis_host(Basis* bs) {
  double L[11][20];
  for (int r = 0; r < 11; ++r)
    for (int c = 0; c < 20; ++c) L[r][c] = 0.0;
  for (int k = 1; k < NCELL; ++k) {
    double xk = (double)k / (double)NCELL;
    L[k - 1][2 * (k - 1)] = xk;
    L[k - 1][2 * (k - 1) + 1] = 1.0;
    L[k - 1][2 * k] = -xk;
    L[k - 1][2 * k + 1] = -1.0;
  }
  L[NCELL - 1][1] = 1.0;
  L[NCELL][2 * (NCELL - 1)] = 1.0;
  L[NCELL][2 * (NCELL - 1) + 1] = 1.0;

  double v[11][20];
  double tau[11];
  for (int i = 0; i < 11; ++i) {
    double alpha = L[i][i];
    double xn2 = 0.0;
    for (int l = i + 1; l < 20; ++l) xn2 += L[i][l] * L[i][l];
    double xnorm = sqrt(xn2);
    for (int l = 0; l < 20; ++l) v[i][l] = 0.0;
    v[i][i] = 1.0;
    if (xnorm == 0.0) {
      tau[i] = 0.0;
    } else {
      double beta = sqrt(alpha * alpha + xn2);
      if (alpha >= 0.0) beta = -beta;        // dlarfg: beta = -sign(alpha)*norm
      tau[i] = (beta - alpha) / beta;
      double sc = 1.0 / (alpha - beta);
      for (int l = i + 1; l < 20; ++l) v[i][l] = L[i][l] * sc;
      L[i][i] = beta;
      for (int j = i + 1; j < 11; ++j) {
        double w = 0.0;
        for (int l = i; l < 20; ++l) w += L[j][l] * v[i][l];
        w *= tau[i];
        for (int l = i; l < 20; ++l) L[j][l] -= w * v[i][l];
      }
    }
  }
  for (int j = 11; j < 20; ++j) {
    double q[20];
    for (int l = 0; l < 20; ++l) q[l] = 0.0;
    q[j] = 1.0;
    for (int i = 10; i >= 0; --i) {
      double w = 0.0;
      for (int l = i; l < 20; ++l) w += v[i][l] * q[l];
      w *= tau[i];
      for (int l = i; l < 20; ++l) q[l] -= w * v[i][l];
    }
    for (int l = 0; l < 20; ++l) bs->Bt[j - 11][l] = (float)q[l];
  }
}

// Fold W3B[r][l] = sum_t w3[r*9+t]*Bt[t][l] (10x20) and b3B[l] = sum_t b3[t]*Bt[t][l]
// per MLP into ws: [m1: 200 W + 20 b][m2: 200 W + 20 b] floats.
__global__ void fold_kernel(const float* __restrict__ w3_1, const float* __restrict__ b3_1,
                            const float* __restrict__ w3_2, const float* __restrict__ b3_2,
                            float* __restrict__ ws, Basis bb) {
  for (int f = threadIdx.x; f < 440; f += THREADS) {
    int m = f / 220;
    int j = f % 220;
    const float* w3 = (m == 0) ? w3_1 : w3_2;
    const float* b3 = (m == 0) ? b3_1 : b3_2;
    float val = 0.0f;
    if (j < 200) {
      int r = j / 20, l = j % 20;
      for (int t = 0; t < DDIM; ++t) val += w3[r * DDIM + t] * bb.Bt[t][l];
    } else {
      int l = j - 200;
      for (int t = 0; t < DDIM; ++t) val += b3[t] * bb.Bt[t][l];
    }
    ws[f] = val;
  }
}

// MLP (1->10->10->10) then A = h2 @ W3B + b3B written to this thread's LDS column.
__device__ __forceinline__ void mlp_A(float xin,
    const float* __restrict__ w0, const float* __restrict__ b0,
    const float* __restrict__ w1, const float* __restrict__ b1,
    const float* __restrict__ w2, const float* __restrict__ b2,
    const float* __restrict__ wbf,     // 220 floats: 100 f32x2 W3B pairs + 10 f32x2 b3B pairs
    f32x2* abcol) {
  const f32x2* w0p = (const f32x2*)w0;
  const f32x2* b0p = (const f32x2*)b0;
  const f32x2* w1p = (const f32x2*)w1;
  const f32x2* b1p = (const f32x2*)b1;
  const f32x2* w2p = (const f32x2*)w2;
  const f32x2* b2p = (const f32x2*)b2;
  const f32x2* WB  = (const f32x2*)wbf;

  f32x2 h0[5], h1[5], h2[5];
  f32x2 xx = {xin, xin};
#pragma unroll
  for (int p = 0; p < 5; ++p) h0[p] = fma2(xx, w0p[p], b0p[p]);

#pragma unroll
  for (int p = 0; p < 5; ++p) h1[p] = b1p[p];
#pragma unroll
  for (int r = 0; r < 10; ++r) {
    float h = h0[r >> 1][r & 1];
    f32x2 hh = {h, h};
#pragma unroll
    for (int p = 0; p < 5; ++p) h1[p] = fma2(hh, w1p[r * 5 + p], h1[p]);
  }
  f32x2 zero = {0.0f, 0.0f};
#pragma unroll
  for (int p = 0; p < 5; ++p) h1[p] = max2(h1[p], zero);

#pragma unroll
  for (int p = 0; p < 5; ++p) h2[p] = b2p[p];
#pragma unroll
  for (int r = 0; r < 10; ++r) {
    float h = h1[r >> 1][r & 1];
    f32x2 hh = {h, h};
#pragma unroll
    for (int p = 0; p < 5; ++p) h2[p] = fma2(hh, w2p[r * 5 + p], h2[p]);
  }
#pragma unroll
  for (int p = 0; p < 5; ++p) h2[p] = max2(h2[p], zero);

  f32x2 acc[NCELL];
#pragma unroll
  for (int l = 0; l < NCELL; ++l) acc[l] = WB[100 + l];   // b3B pairs
#pragma unroll
  for (int r = 0; r < 10; ++r) {
    float h = h2[r >> 1][r & 1];
    f32x2 hh = {h, h};
#pragma unroll
    for (int l = 0; l < NCELL; ++l) acc[l] = fma2(hh, WB[r * 10 + l], acc[l]);
  }
#pragma unroll
  for (int l = 0; l < NCELL; ++l) abcol[l * THREADS] = acc[l];
}

// Cell-hop loop, exploiting CPA invariants to minimize per-iteration work:
//  - v is CONTINUOUS across cells (the constraint matrix L encodes exactly
//    this), so after a crossing v(entry_new) == vxc_prev: no per-iter
//    v=fma(a,phi,b), and rcp(v) issues at the END of the previous iteration
//    (off the decision chain).
//  - trajectory is MONOTONE (v=0 are fixed points; ratio<0 hits the 1e-30
//    clamp -> no-cross, same as reference): dir/d01 hoisted, xc += d01,
//    c += dirI; no per-iter sign/cvt/cn logic.
//  - v(0)=v(1)=0 by basis construction => boundary ping-pong can't fire:
//    frozen logic deleted (kept c clamp as cheap insurance).
//  - exp/evolve deferred post-loop (r7); at loop exit every lane's registers
//    (a,b) hold its terminal cell (vote passes only when all lanes stopped),
//    and phiC is the terminal entry point: fin needs NO LDS re-reads.
//  - guards preserved: |a|<1e-10 lin path (wave-uniform branch), ratio clamp
//    1e-30, |v|<1e-14 -> no-cross (terminal).
__device__ __forceinline__ void flow_dev(float x0, const f32x2* abcol,
                                         float& zo, float& ldo) {
  int c = (int)(x0 * 10.0f);
  c = c < 0 ? 0 : (c > 9 ? 9 : c);
  f32x2 ab = abcol[c * THREADS];
  float a = ab[0], b = ab[1];
  float v0 = fmaf(a, x0, b);
  bool right = (v0 >= 0.0f);
  float d01 = right ? 0.1f : -0.1f;
  int dirI = right ? 1 : -1;
  float xc = (float)(right ? (c + 1) : c) * 0.1f;
  float rv = __builtin_amdgcn_rcpf(v0);
  bool tinyP = fabsf(v0) < 1e-14f;
  float phiC = x0;           // entry point of current cell
  float t = 1.0f;            // t > 0 <=> active (terminal sets t = 0)
  float ld = 0.0f;
  float trem = 0.0f;

  for (int it = 0; it < NCELL; ++it) {
    float vxc = fmaf(a, xc, b);
    float ratio = fmaxf(vxc * rv, 1e-30f);
    float l = __logf(ratio);                       // v_log_f32
    bool lin = fabsf(a) < 1e-10f;
    float ra = __builtin_amdgcn_rcpf(lin ? 1.0f : a);
    float thit = l * ra;
    if (__any(lin)) {                              // ~never taken
      float sb = (fabsf(b) < 1e-30f) ? 1.0f : b;
      float tl = (xc - phiC) * __builtin_amdgcn_rcpf(sb);
      thit = lin ? tl : thit;
    }
    bool active = t > 0.0f;
    bool cross = (thit < t) && !tinyP;
    bool ac = active && cross;
    bool term = active && !cross;
    trem = term ? t : trem;
    ld += ac ? l : 0.0f;
    float tn = t - thit;
    t = active ? (cross ? tn : 0.0f) : t;
    phiC = ac ? xc : phiC;
    c = ac ? (c + dirI) : c;
    c = c < 0 ? 0 : (c > 9 ? 9 : c);               // fp-safety only
    xc = ac ? (xc + d01) : xc;
    if (__all(t <= 0.0f)) break;
    ab = abcol[c * THREADS];
    a = ab[0]; b = ab[1];
    tinyP = fabsf(vxc) < 1e-14f;                   // v(entry_new) == vxc (continuity)
    rv = __builtin_amdgcn_rcpf(vxc);               // issued off the next chain
  }
  // post-loop: evolve once inside the terminal cell (reference formulas);
  // (a,b) already in registers, phiC is the entry point.
  bool done = trem > 0.0f;
  bool linf = fabsf(a) < 1e-10f;
  float rsaf = __builtin_amdgcn_rcpf(linf ? 1.0f : a);
  float bsa = b * rsaf;
  float E = __expf(a * trem);                      // the ONLY exp in the flow
  float pnl = fmaf(phiC + bsa, E, -bsa);
  float pli = fmaf(b, trem, phiC);
  float p1 = linf ? pli : pnl;
  zo = done ? p1 : phiC;
  ldo = ld + (done ? a * trem : 0.0f);
}

__global__ __launch_bounds__(THREADS, 4) void cpab2d_kernel(
    const float* __restrict__ x,
    const float* __restrict__ m1w0, const float* __restrict__ m1b0,
    const float* __restrict__ m1w1, const float* __restrict__ m1b1,
    const float* __restrict__ m1w2, const float* __restrict__ m1b2,
    const float* __restrict__ m2w0, const float* __restrict__ m2b0,
    const float* __restrict__ m2w1, const float* __restrict__ m2b1,
    const float* __restrict__ m2w2, const float* __restrict__ m2b2,
    const float* __restrict__ wsf,
    float* __restrict__ out, int n) {
  __shared__ f32x2 AB[NCELL][THREADS];   // [cell][tid] -> conflict-free dyn read
  int i = blockIdx.x * THREADS + threadIdx.x;
  if (i >= n) return;

  float2 xi = reinterpret_cast<const float2*>(x)[i];
  // xs = x[:, [1,0]]: x1 = x[:,1], x2 = x[:,0]; both clipped first
  float x2v = fminf(fmaxf(xi.x, 1e-7f), 1.0f - 1e-7f);
  float x1v = fminf(fmaxf(xi.y, 1e-7f), 1.0f - 1e-7f);

  f32x2* abcol = &AB[0][threadIdx.x];

  // theta2 = mlp(x1, m2); z2,g2 = flow(x2, theta2)
  mlp_A(x1v, m2w0, m2b0, m2w1, m2b1, m2w2, m2b2, wsf + 220, abcol);
  float z2, ld2;
  flow_dev(x2v, abcol, z2, ld2);

  // theta1 = mlp(z2, m1); z1,g1 = flow(x1, theta1)
  mlp_A(z2, m1w0, m1b0, m1w1, m1b1, m1w2, m1b2, wsf, abcol);
  float z1, ld1;
  flow_dev(x1v, abcol, z1, ld1);

  // z = [z2, z1]; log_dz_dx = [ld2, ld1]
  reinterpret_cast<float2*>(out)[i] = make_float2(z2, z1);
  reinterpret_cast<float2*>(out + 2 * (size_t)n)[i] = make_float2(ld2, ld1);
}

extern "C" void kernel_launch(void* const* d_in, const int* in_sizes, int n_in,
                              void* d_out, int out_size, void* d_ws, size_t ws_size,
                              hipStream_t stream) {
  const float* x    = (const float*)d_in[0];
  const float* m1w0 = (const float*)d_in[1];
  const float* m1b0 = (const float*)d_in[2];
  const float* m1w1 = (const float*)d_in[3];
  const float* m1b1 = (const float*)d_in[4];
  const float* m1w2 = (const float*)d_in[5];
  const float* m1b2 = (const float*)d_in[6];
  const float* m1w3 = (const float*)d_in[7];
  const float* m1b3 = (const float*)d_in[8];
  const float* m2w0 = (const float*)d_in[9];
  const float* m2b0 = (const float*)d_in[10];
  const float* m2w1 = (const float*)d_in[11];
  const float* m2b1 = (const float*)d_in[12];
  const float* m2w2 = (const float*)d_in[13];
  const float* m2b2 = (const float*)d_in[14];
  const float* m2w3 = (const float*)d_in[15];
  const float* m2b3 = (const float*)d_in[16];
  float* out = (float*)d_out;
  float* wsf = (float*)d_ws;
  int n = in_sizes[0] / 2;

  Basis bs;
  compute_basis_host(&bs);

  fold_kernel<<<1, THREADS, 0, stream>>>(m1w3, m1b3, m2w3, m2b3, wsf, bs);

  dim3 grid((n + THREADS - 1) / THREADS), block(THREADS);
  cpab2d_kernel<<<grid, block, 0, stream>>>(
      x, m1w0, m1b0, m1w1, m1b1, m1w2, m1b2,
      m2w0, m2b0, m2w1, m2b1, m2w2, m2b2,
      wsf, out, n);
}

// Round 10
// 51.219 us; speedup vs baseline: 1.1505x; 1.1085x over previous
//
#include <hip/hip_runtime.h>
#include <cmath>

#define THREADS 256
#define NCELL 10
#define DDIM 9

typedef float f32x2 __attribute__((ext_vector_type(2)));

__device__ __forceinline__ f32x2 fma2(f32x2 a, f32x2 b, f32x2 c) {
  return __builtin_elementwise_fma(a, b, c);   // v_pk_fma_f32 on gfx950
}
__device__ __forceinline__ f32x2 max2(f32x2 a, f32x2 b) {
  return __builtin_elementwise_max(a, b);      // v_pk_max_f32
}

struct Basis { float Bt[DDIM][2 * NCELL]; }; // Bt[t][l] = B[l][t]

// Reproduce numpy.linalg.svd(L) Vt[11:] rows: LAPACK dgesdd Path 4t leaves
// rows m..n-1 of VT equal to the LQ-factorization orthogonal complement
// (dgelqf + dorglq). Replicate dlarfg/dgelq2/dorgl2 in double precision.
static void compute_basis_host(Basis* bs) {
  double L[11][20];
  for (int r = 0; r < 11; ++r)
    for (int c = 0; c < 20; ++c) L[r][c] = 0.0;
  for (int k = 1; k < NCELL; ++k) {
    double xk = (double)k / (double)NCELL;
    L[k - 1][2 * (k - 1)] = xk;
    L[k - 1][2 * (k - 1) + 1] = 1.0;
    L[k - 1][2 * k] = -xk;
    L[k - 1][2 * k + 1] = -1.0;
  }
  L[NCELL - 1][1] = 1.0;
  L[NCELL][2 * (NCELL - 1)] = 1.0;
  L[NCELL][2 * (NCELL - 1) + 1] = 1.0;

  double v[11][20];
  double tau[11];
  for (int i = 0; i < 11; ++i) {
    double alpha = L[i][i];
    double xn2 = 0.0;
    for (int l = i + 1; l < 20; ++l) xn2 += L[i][l] * L[i][l];
    double xnorm = sqrt(xn2);
    for (int l = 0; l < 20; ++l) v[i][l] = 0.0;
    v[i][i] = 1.0;
    if (xnorm == 0.0) {
      tau[i] = 0.0;
    } else {
      double beta = sqrt(alpha * alpha + xn2);
      if (alpha >= 0.0) beta = -beta;        // dlarfg: beta = -sign(alpha)*norm
      tau[i] = (beta - alpha) / beta;
      double sc = 1.0 / (alpha - beta);
      for (int l = i + 1; l < 20; ++l) v[i][l] = L[i][l] * sc;
      L[i][i] = beta;
      for (int j = i + 1; j < 11; ++j) {
        double w = 0.0;
        for (int l = i; l < 20; ++l) w += L[j][l] * v[i][l];
        w *= tau[i];
        for (int l = i; l < 20; ++l) L[j][l] -= w * v[i][l];
      }
    }
  }
  for (int j = 11; j < 20; ++j) {
    double q[20];
    for (int l = 0; l < 20; ++l) q[l] = 0.0;
    q[j] = 1.0;
    for (int i = 10; i >= 0; --i) {
      double w = 0.0;
      for (int l = i; l < 20; ++l) w += v[i][l] * q[l];
      w *= tau[i];
      for (int l = i; l < 20; ++l) q[l] -= w * v[i][l];
    }
    for (int l = 0; l < 20; ++l) bs->Bt[j - 11][l] = (float)q[l];
  }
}

// Per-MLP folds (240 floats each; m1 at ws[0], m2 at ws[240]):
//  [0:10)   W01[j]  = sum_r w0[r]*w1[r,j]          (layer0+1 fold: NO ReLU between)
//  [10:20)  B01[j]  = sum_r b0[r]*w1[r,j] + b1[j]
//  [20:220) W3B[r][l] = sum_t w3[r,t]*Bt[t][l]     (last layer + basis fold)
//  [220:240) b3B[l] = sum_t b3[t]*Bt[t][l]
__global__ void fold_kernel(
    const float* __restrict__ w0_1, const float* __restrict__ b0_1,
    const float* __restrict__ w1_1, const float* __restrict__ b1_1,
    const float* __restrict__ w3_1, const float* __restrict__ b3_1,
    const float* __restrict__ w0_2, const float* __restrict__ b0_2,
    const float* __restrict__ w1_2, const float* __restrict__ b1_2,
    const float* __restrict__ w3_2, const float* __restrict__ b3_2,
    float* __restrict__ ws, Basis bb) {
  for (int f = threadIdx.x; f < 480; f += THREADS) {
    int m = f / 240;
    int j = f % 240;
    const float* w0 = (m == 0) ? w0_1 : w0_2;
    const float* b0 = (m == 0) ? b0_1 : b0_2;
    const float* w1 = (m == 0) ? w1_1 : w1_2;
    const float* b1 = (m == 0) ? b1_1 : b1_2;
    const float* w3 = (m == 0) ? w3_1 : w3_2;
    const float* b3 = (m == 0) ? b3_1 : b3_2;
    float val = 0.0f;
    if (j < 10) {
      for (int r = 0; r < 10; ++r) val += w0[r] * w1[r * 10 + j];
    } else if (j < 20) {
      int jj = j - 10;
      for (int r = 0; r < 10; ++r) val += b0[r] * w1[r * 10 + jj];
      val += b1[jj];
    } else if (j < 220) {
      int jj = j - 20;
      int r = jj / 20, l = jj % 20;
      for (int t = 0; t < DDIM; ++t) val += w3[r * DDIM + t] * bb.Bt[t][l];
    } else {
      int l = j - 220;
      for (int t = 0; t < DDIM; ++t) val += b3[t] * bb.Bt[t][l];
    }
    ws[f] = val;
  }
}

// Folded MLP: h1 = relu(x*W01+B01); h2 = relu(h1@w2+b2); A = h2@W3B + b3B.
// Writes (a,b) per cell to this thread's LDS column; returns min|a| for the
// hoisted lin-vote.
__device__ __forceinline__ void mlp_A(float xin,
    const float* __restrict__ w2, const float* __restrict__ b2,
    const float* __restrict__ wbf,     // 240 floats = 120 f32x2 (layout above)
    f32x2* abcol, float& amin) {
  const f32x2* W01 = (const f32x2*)wbf;         // [0:5)
  const f32x2* B01 = W01 + 5;                   // [5:10)
  const f32x2* W3B = W01 + 10;                  // [10:110)
  const f32x2* B3B = W01 + 110;                 // [110:120)
  const f32x2* w2p = (const f32x2*)w2;
  const f32x2* b2p = (const f32x2*)b2;

  f32x2 h1[5], h2[5];
  f32x2 xx = {xin, xin};
  f32x2 zero = {0.0f, 0.0f};
#pragma unroll
  for (int p = 0; p < 5; ++p) h1[p] = max2(fma2(xx, W01[p], B01[p]), zero);

#pragma unroll
  for (int p = 0; p < 5; ++p) h2[p] = b2p[p];
#pragma unroll
  for (int r = 0; r < 10; ++r) {
    float h = h1[r >> 1][r & 1];
    f32x2 hh = {h, h};
#pragma unroll
    for (int p = 0; p < 5; ++p) h2[p] = fma2(hh, w2p[r * 5 + p], h2[p]);
  }
#pragma unroll
  for (int p = 0; p < 5; ++p) h2[p] = max2(h2[p], zero);

  f32x2 acc[NCELL];
#pragma unroll
  for (int l = 0; l < NCELL; ++l) acc[l] = B3B[l];
#pragma unroll
  for (int r = 0; r < 10; ++r) {
    float h = h2[r >> 1][r & 1];
    f32x2 hh = {h, h};
#pragma unroll
    for (int l = 0; l < NCELL; ++l) acc[l] = fma2(hh, W3B[r * 10 + l], acc[l]);
  }
  float mn = 1e30f;
#pragma unroll
  for (int l = 0; l < NCELL; ++l) {
    abcol[l * THREADS] = acc[l];
    mn = fminf(mn, fabsf(acc[l][0]));
  }
  amin = mn;
}

// Cell-hop loop. r9 invariants (v continuous across cells, monotone direction,
// deferred exp) plus:
//  - ld TELESCOPED: sum of log(ratio_k) over crossed cells == log(v_term/v0)
//    by continuity (clamps only fire on non-crossed cells), so no per-iter
//    accumulate; one log post-loop.
//  - speculative prefetch of clamp(c+dir)'s (a,b) and rcp(a) each iteration:
//    the 120cy LDS read and the rcp are fully off the decision chain.
//  - lin (|a|<1e-10) vote hoisted out of the loop (min|a| from mlp_A).
// Guards preserved: ratio clamp 1e-30, |v|<1e-14 -> no-cross, lin fixup path.
__device__ __forceinline__ void flow_dev(float x0, const f32x2* abcol,
                                         bool has_lin, float& zo, float& ldo) {
  int c = (int)(x0 * 10.0f);
  c = c < 0 ? 0 : (c > 9 ? 9 : c);
  f32x2 ab = abcol[c * THREADS];
  float a = ab[0], b = ab[1];
  float v0 = fmaf(a, x0, b);
  bool right = (v0 >= 0.0f);
  float d01 = right ? 0.1f : -0.1f;
  int dirI = right ? 1 : -1;
  float xc = (float)(right ? (c + 1) : c) * 0.1f;
  float rv0 = __builtin_amdgcn_rcpf(v0);
  float rv = rv0;
  float vcur = v0;
  bool tiny = fabsf(v0) < 1e-14f;
  float ra = __builtin_amdgcn_rcpf(a);
  float phiC = x0;           // entry point of current cell
  float t = 1.0f;            // t > 0 <=> active (terminal sets t = 0)
  float trem = 0.0f;

  // prefetch next cell in travel direction
  int cn = c + dirI; cn = cn < 0 ? 0 : (cn > 9 ? 9 : cn);
  f32x2 abn = abcol[cn * THREADS];
  float ran = __builtin_amdgcn_rcpf(abn[0]);

  for (int it = 0; it < NCELL; ++it) {
    float vxc = fmaf(a, xc, b);
    float ratio = fmaxf(vxc * rv, 1e-30f);
    float l = __logf(ratio);                       // v_log_f32
    float thit = l * ra;
    if (has_lin) {                                 // hoisted; ~never taken
      bool lin = fabsf(a) < 1e-10f;
      float sb = (fabsf(b) < 1e-30f) ? 1.0f : b;
      float tl = (xc - phiC) * __builtin_amdgcn_rcpf(sb);
      thit = lin ? tl : thit;
    }
    bool active = t > 0.0f;
    bool cross = (thit < t) && !tiny;
    bool ac = active && cross;
    bool term = active && !cross;
    trem = term ? t : trem;
    float tn = t - thit;
    t = active ? (cross ? tn : 0.0f) : t;
    phiC = ac ? xc : phiC;
    vcur = ac ? vxc : vcur;
    float rvn = __builtin_amdgcn_rcpf(vxc);        // off-chain
    rv = ac ? rvn : rv;
    tiny = ac ? (fabsf(vxc) < 1e-14f) : tiny;
    a = ac ? abn[0] : a;
    b = ac ? abn[1] : b;
    ra = ac ? ran : ra;
    xc = ac ? (xc + d01) : xc;
    c = ac ? cn : c;
    if (__all(t <= 0.0f)) break;
    int cnn = c + dirI; cnn = cnn < 0 ? 0 : (cnn > 9 ? 9 : cnn);
    abn = abcol[cnn * THREADS];                    // prefetch for next iter
    ran = __builtin_amdgcn_rcpf(abn[0]);
    cn = cnn;
  }
  // post-loop: telescoped ld + one evolve inside the terminal cell
  // (reference formulas); (a,b)/phiC already in registers.
  bool done = trem > 0.0f;
  float ld = __logf(fmaxf(vcur * rv0, 1e-30f));    // == sum of crossed log-ratios
  bool linf = fabsf(a) < 1e-10f;
  float rsaf = __builtin_amdgcn_rcpf(linf ? 1.0f : a);
  float bsa = b * rsaf;
  float E = __expf(a * trem);                      // the ONLY exp in the flow
  float pnl = fmaf(phiC + bsa, E, -bsa);
  float pli = fmaf(b, trem, phiC);
  float p1 = linf ? pli : pnl;
  zo = done ? p1 : phiC;
  ldo = ld + (done ? a * trem : 0.0f);
}

__global__ __launch_bounds__(THREADS, 4) void cpab2d_kernel(
    const float* __restrict__ x,
    const float* __restrict__ m1w2, const float* __restrict__ m1b2,
    const float* __restrict__ m2w2, const float* __restrict__ m2b2,
    const float* __restrict__ wsf,
    float* __restrict__ out, int n) {
  __shared__ f32x2 AB[NCELL][THREADS];   // [cell][tid] -> conflict-free dyn read
  int i = blockIdx.x * THREADS + threadIdx.x;
  if (i >= n) return;

  float2 xi = reinterpret_cast<const float2*>(x)[i];
  // xs = x[:, [1,0]]: x1 = x[:,1], x2 = x[:,0]; both clipped first
  float x2v = fminf(fmaxf(xi.x, 1e-7f), 1.0f - 1e-7f);
  float x1v = fminf(fmaxf(xi.y, 1e-7f), 1.0f - 1e-7f);

  f32x2* abcol = &AB[0][threadIdx.x];
  float amin;

  // theta2 = mlp(x1, m2); z2,g2 = flow(x2, theta2)
  mlp_A(x1v, m2w2, m2b2, wsf + 240, abcol, amin);
  bool hl2 = __any(amin < 1e-10f);
  float z2, ld2;
  flow_dev(x2v, abcol, hl2, z2, ld2);

  // theta1 = mlp(z2, m1); z1,g1 = flow(x1, theta1)
  mlp_A(z2, m1w2, m1b2, wsf, abcol, amin);
  bool hl1 = __any(amin < 1e-10f);
  float z1, ld1;
  flow_dev(x1v, abcol, hl1, z1, ld1);

  // z = [z2, z1]; log_dz_dx = [ld2, ld1]
  reinterpret_cast<float2*>(out)[i] = make_float2(z2, z1);
  reinterpret_cast<float2*>(out + 2 * (size_t)n)[i] = make_float2(ld2, ld1);
}

extern "C" void kernel_launch(void* const* d_in, const int* in_sizes, int n_in,
                              void* d_out, int out_size, void* d_ws, size_t ws_size,
                              hipStream_t stream) {
  const float* x    = (const float*)d_in[0];
  const float* m1w0 = (const float*)d_in[1];
  const float* m1b0 = (const float*)d_in[2];
  const float* m1w1 = (const float*)d_in[3];
  const float* m1b1 = (const float*)d_in[4];
  const float* m1w2 = (const float*)d_in[5];
  const float* m1b2 = (const float*)d_in[6];
  const float* m1w3 = (const float*)d_in[7];
  const float* m1b3 = (const float*)d_in[8];
  const float* m2w0 = (const float*)d_in[9];
  const float* m2b0 = (const float*)d_in[10];
  const float* m2w1 = (const float*)d_in[11];
  const float* m2b1 = (const float*)d_in[12];
  const float* m2w2 = (const float*)d_in[13];
  const float* m2b2 = (const float*)d_in[14];
  const float* m2w3 = (const float*)d_in[15];
  const float* m2b3 = (const float*)d_in[16];
  float* out = (float*)d_out;
  float* wsf = (float*)d_ws;
  int n = in_sizes[0] / 2;

  Basis bs;
  compute_basis_host(&bs);

  fold_kernel<<<1, THREADS, 0, stream>>>(
      m1w0, m1b0, m1w1, m1b1, m1w3, m1b3,
      m2w0, m2b0, m2w1, m2b1, m2w3, m2b3, wsf, bs);

  dim3 grid((n + THREADS - 1) / THREADS), block(THREADS);
  cpab2d_kernel<<<grid, block, 0, stream>>>(
      x, m1w2, m1b2, m2w2, m2b2, wsf, out, n);
}

// Round 11
// 45.817 us; speedup vs baseline: 1.2861x; 1.1179x over previous
//
#include <hip/hip_runtime.h>
#include <cmath>

#define THREADS 256
#define NCELL 10
#define DDIM 9

typedef float f32x2 __attribute__((ext_vector_type(2)));

__device__ __forceinline__ f32x2 fma2(f32x2 a, f32x2 b, f32x2 c) {
  return __builtin_elementwise_fma(a, b, c);   // v_pk_fma_f32 on gfx950
}
__device__ __forceinline__ f32x2 max2(f32x2 a, f32x2 b) {
  return __builtin_elementwise_max(a, b);      // v_pk_max_f32
}

struct Basis { float Bt[DDIM][2 * NCELL]; }; // Bt[t][l] = B[l][t]

// Reproduce numpy.linalg.svd(L) Vt[11:] rows: LAPACK dgesdd Path 4t leaves
// rows m..n-1 of VT equal to the LQ-factorization orthogonal complement
// (dgelqf + dorglq). Replicate dlarfg/dgelq2/dorgl2 in double precision.
static void compute_basis_host(Basis* bs) {
  double L[11][20];
  for (int r = 0; r < 11; ++r)
    for (int c = 0; c < 20; ++c) L[r][c] = 0.0;
  for (int k = 1; k < NCELL; ++k) {
    double xk = (double)k / (double)NCELL;
    L[k - 1][2 * (k - 1)] = xk;
    L[k - 1][2 * (k - 1) + 1] = 1.0;
    L[k - 1][2 * k] = -xk;
    L[k - 1][2 * k + 1] = -1.0;
  }
  L[NCELL - 1][1] = 1.0;
  L[NCELL][2 * (NCELL - 1)] = 1.0;
  L[NCELL][2 * (NCELL - 1) + 1] = 1.0;

  double v[11][20];
  double tau[11];
  for (int i = 0; i < 11; ++i) {
    double alpha = L[i][i];
    double xn2 = 0.0;
    for (int l = i + 1; l < 20; ++l) xn2 += L[i][l] * L[i][l];
    double xnorm = sqrt(xn2);
    for (int l = 0; l < 20; ++l) v[i][l] = 0.0;
    v[i][i] = 1.0;
    if (xnorm == 0.0) {
      tau[i] = 0.0;
    } else {
      double beta = sqrt(alpha * alpha + xn2);
      if (alpha >= 0.0) beta = -beta;        // dlarfg: beta = -sign(alpha)*norm
      tau[i] = (beta - alpha) / beta;
      double sc = 1.0 / (alpha - beta);
      for (int l = i + 1; l < 20; ++l) v[i][l] = L[i][l] * sc;
      L[i][i] = beta;
      for (int j = i + 1; j < 11; ++j) {
        double w = 0.0;
        for (int l = i; l < 20; ++l) w += L[j][l] * v[i][l];
        w *= tau[i];
        for (int l = i; l < 20; ++l) L[j][l] -= w * v[i][l];
      }
    }
  }
  for (int j = 11; j < 20; ++j) {
    double q[20];
    for (int l = 0; l < 20; ++l) q[l] = 0.0;
    q[j] = 1.0;
    for (int i = 10; i >= 0; --i) {
      double w = 0.0;
      for (int l = i; l < 20; ++l) w += v[i][l] * q[l];
      w *= tau[i];
      for (int l = i; l < 20; ++l) q[l] -= w * v[i][l];
    }
    for (int l = 0; l < 20; ++l) bs->Bt[j - 11][l] = (float)q[l];
  }
}

// Per-MLP folds (130 floats each; m1 at ws[0], m2 at ws[130]):
//  [0:10)    W01[j]  = sum_r w0[r]*w1[r,j]       (layer0+1 fold: NO ReLU between)
//  [10:20)   B01[j]  = sum_r b0[r]*w1[r,j] + b1[j]
//  [20:120)  W3V[r][k] = sum_t w3[r,t]*VB[t][k+1], k=0..8; k=9 -> 0 (v10 pad)
//  [120:130) B3V[k]  = sum_t b3[t]*VB[t][k+1],  k=0..8; k=9 -> 0
//  where VB[t][j] = Bt[t][2j]*(j/10) + Bt[t][2j+1] = basis field at grid pt j.
//  (v-grid reparam: the CPA field's 9 DOF are v(j/10), j=1..9; v(0)=v(1)=0.)
__global__ void fold_kernel(
    const float* __restrict__ w0_1, const float* __restrict__ b0_1,
    const float* __restrict__ w1_1, const float* __restrict__ b1_1,
    const float* __restrict__ w3_1, const float* __restrict__ b3_1,
    const float* __restrict__ w0_2, const float* __restrict__ b0_2,
    const float* __restrict__ w1_2, const float* __restrict__ b1_2,
    const float* __restrict__ w3_2, const float* __restrict__ b3_2,
    float* __restrict__ ws, Basis bb) {
  for (int f = threadIdx.x; f < 260; f += THREADS) {
    int m = f / 130;
    int j = f % 130;
    const float* w0 = (m == 0) ? w0_1 : w0_2;
    const float* b0 = (m == 0) ? b0_1 : b0_2;
    const float* w1 = (m == 0) ? w1_1 : w1_2;
    const float* w3 = (m == 0) ? w3_1 : w3_2;
    const float* b3 = (m == 0) ? b3_1 : b3_2;
    const float* b1 = (m == 0) ? b1_1 : b1_2;
    float val = 0.0f;
    if (j < 10) {
      for (int r = 0; r < 10; ++r) val += w0[r] * w1[r * 10 + j];
    } else if (j < 20) {
      int jj = j - 10;
      for (int r = 0; r < 10; ++r) val += b0[r] * w1[r * 10 + jj];
      val += b1[jj];
    } else if (j < 120) {
      int jj = j - 20;
      int r = jj / 10, k = jj % 10;
      if (k < 9) {
        float g = (float)(k + 1) * 0.1f;
        for (int t = 0; t < DDIM; ++t)
          val += w3[r * DDIM + t] * (bb.Bt[t][2 * (k + 1)] * g + bb.Bt[t][2 * (k + 1) + 1]);
      }
    } else {
      int k = j - 120;
      if (k < 9) {
        float g = (float)(k + 1) * 0.1f;
        for (int t = 0; t < DDIM; ++t)
          val += b3[t] * (bb.Bt[t][2 * (k + 1)] * g + bb.Bt[t][2 * (k + 1) + 1]);
      }
    }
    ws[f] = val;
  }
}

// Folded MLP: h1 = relu(x*W01+B01); h2 = relu(h1@w2+b2); v1..v9 = h2@W3V+B3V
// (v0 = v10 = 0 by construction). Derive per cell: a_c = 10*(v[c+1]-v[c]),
// b_c = v[c] - a_c*(c/10) — identical to theta@B^T in exact arithmetic (the
// basis satisfies L's continuity rows). Writes (a,b) to this thread's LDS
// column; returns min|a| for the hoisted lin-vote.
__device__ __forceinline__ void mlp_A(float xin,
    const float* __restrict__ w2, const float* __restrict__ b2,
    const float* __restrict__ wbf,     // 130 floats (layout above)
    f32x2* abcol, float& amin) {
  const f32x2* W01 = (const f32x2*)wbf;         // [0:5)
  const f32x2* B01 = W01 + 5;                   // [5:10)
  const f32x2* W3V = W01 + 10;                  // [10:60): 10 rows x 5 pairs
  const f32x2* B3V = W01 + 60;                  // [60:65)
  const f32x2* w2p = (const f32x2*)w2;
  const f32x2* b2p = (const f32x2*)b2;

  f32x2 h1[5], h2[5];
  f32x2 xx = {xin, xin};
  f32x2 zero = {0.0f, 0.0f};
#pragma unroll
  for (int p = 0; p < 5; ++p) h1[p] = max2(fma2(xx, W01[p], B01[p]), zero);

#pragma unroll
  for (int p = 0; p < 5; ++p) h2[p] = b2p[p];
#pragma unroll
  for (int r = 0; r < 10; ++r) {
    float h = h1[r >> 1][r & 1];
    f32x2 hh = {h, h};
#pragma unroll
    for (int p = 0; p < 5; ++p) h2[p] = fma2(hh, w2p[r * 5 + p], h2[p]);
  }
#pragma unroll
  for (int p = 0; p < 5; ++p) h2[p] = max2(h2[p], zero);

  f32x2 vp[5];                                   // (v1,v2)..(v9,v10=0)
#pragma unroll
  for (int p = 0; p < 5; ++p) vp[p] = B3V[p];
#pragma unroll
  for (int r = 0; r < 10; ++r) {
    float h = h2[r >> 1][r & 1];
    f32x2 hh = {h, h};
#pragma unroll
    for (int p = 0; p < 5; ++p) vp[p] = fma2(hh, W3V[r * 5 + p], vp[p]);
  }

  float v[NCELL + 1];
  v[0] = 0.0f;
#pragma unroll
  for (int k = 1; k <= NCELL; ++k) v[k] = vp[(k - 1) >> 1][(k - 1) & 1];

  float mn = 1e30f;
#pragma unroll
  for (int c = 0; c < NCELL; ++c) {
    float ac = (v[c + 1] - v[c]) * 10.0f;
    float bc = fmaf(ac, -(float)c * 0.1f, v[c]);
    f32x2 ab; ab[0] = ac; ab[1] = bc;
    abcol[c * THREADS] = ab;
    mn = fminf(mn, fabsf(ac));
  }
  amin = mn;
}

// Freeze-form cell-hop loop. All r10 invariants (v continuous -> v_entry :=
// vxc_prev register-exact, telescoped ld, monotone direction, deferred exp,
// LDS prefetch, hoisted lin-vote) plus:
//  - NO active/term/trem bookkeeping: a terminal lane has cross=false and its
//    state is a fixed point of the update (same thit, same t -> cross stays
//    false). Post-loop trem = t, done = !cross_final. Exit vote __all(!cross).
//  - vcur deleted: v_term recomputed post-loop as fma(a, phiC, b).
// Guards preserved: ratio clamp 1e-30, |v|<1e-14 tiny -> no-cross, lin fixup.
__device__ __forceinline__ void flow_dev(float x0, const f32x2* abcol,
                                         bool has_lin, float& zo, float& ldo) {
  int c = (int)(x0 * 10.0f);
  c = c < 0 ? 0 : (c > 9 ? 9 : c);
  f32x2 ab = abcol[c * THREADS];
  float a = ab[0], b = ab[1];
  float v0 = fmaf(a, x0, b);
  bool right = (v0 >= 0.0f);
  float d01 = right ? 0.1f : -0.1f;
  int dirI = right ? 1 : -1;
  float xc = (float)(right ? (c + 1) : c) * 0.1f;
  float rv0 = __builtin_amdgcn_rcpf(v0);
  float rv = rv0;
  bool tiny = fabsf(v0) < 1e-14f;
  float ra = __builtin_amdgcn_rcpf(a);
  float phiC = x0;           // entry point of current cell
  float t = 1.0f;            // remaining time; freezes at terminal
  bool cross = false;

  // prefetch next cell in travel direction
  int cn = c + dirI; cn = cn < 0 ? 0 : (cn > 9 ? 9 : cn);
  f32x2 abn = abcol[cn * THREADS];
  float ran = __builtin_amdgcn_rcpf(abn[0]);

  for (int it = 0; it < NCELL; ++it) {
    float vxc = fmaf(a, xc, b);
    float ratio = fmaxf(vxc * rv, 1e-30f);
    float l = __logf(ratio);                       // v_log_f32
    float thit = l * ra;
    if (has_lin) {                                 // hoisted; ~never taken
      bool lin = fabsf(a) < 1e-10f;
      float sb = (fabsf(b) < 1e-30f) ? 1.0f : b;
      float tl = (xc - phiC) * __builtin_amdgcn_rcpf(sb);
      thit = lin ? tl : thit;
    }
    cross = (thit < t) && !tiny;
    t = cross ? (t - thit) : t;
    phiC = cross ? xc : phiC;
    float rvn = __builtin_amdgcn_rcpf(vxc);        // off-chain
    rv = cross ? rvn : rv;
    tiny = cross ? (fabsf(vxc) < 1e-14f) : tiny;
    a = cross ? abn[0] : a;
    b = cross ? abn[1] : b;
    ra = cross ? ran : ra;
    xc = cross ? (xc + d01) : xc;
    c = cross ? cn : c;
    if (__all(!cross)) break;
    int cnn = c + dirI; cnn = cnn < 0 ? 0 : (cnn > 9 ? 9 : cnn);
    abn = abcol[cnn * THREADS];                    // prefetch for next iter
    ran = __builtin_amdgcn_rcpf(abn[0]);
    cn = cnn;
  }
  // post-loop: telescoped ld (v_term/v0) + one evolve inside the terminal
  // cell (reference formulas); (a,b)/phiC/t all live in registers.
  bool done = !cross;        // false only if still crossing at exhaustion
  float vterm = fmaf(a, phiC, b);
  float ld = __logf(fmaxf(vterm * rv0, 1e-30f));   // == sum of crossed log-ratios
  bool linf = fabsf(a) < 1e-10f;
  float rsaf = __builtin_amdgcn_rcpf(linf ? 1.0f : a);
  float bsa = b * rsaf;
  float E = __expf(a * t);                         // the ONLY exp in the flow
  float pnl = fmaf(phiC + bsa, E, -bsa);
  float pli = fmaf(b, t, phiC);
  float p1 = linf ? pli : pnl;
  zo = done ? p1 : phiC;
  ldo = ld + (done ? a * t : 0.0f);
}

__global__ __launch_bounds__(THREADS, 4) void cpab2d_kernel(
    const float* __restrict__ x,
    const float* __restrict__ m1w2, const float* __restrict__ m1b2,
    const float* __restrict__ m2w2, const float* __restrict__ m2b2,
    const float* __restrict__ wsf,
    float* __restrict__ out, int n) {
  __shared__ f32x2 AB[NCELL][THREADS];   // [cell][tid] -> conflict-free dyn read
  int i = blockIdx.x * THREADS + threadIdx.x;
  if (i >= n) return;

  float2 xi = reinterpret_cast<const float2*>(x)[i];
  // xs = x[:, [1,0]]: x1 = x[:,1], x2 = x[:,0]; both clipped first
  float x2v = fminf(fmaxf(xi.x, 1e-7f), 1.0f - 1e-7f);
  float x1v = fminf(fmaxf(xi.y, 1e-7f), 1.0f - 1e-7f);

  f32x2* abcol = &AB[0][threadIdx.x];
  float amin;

  // theta2 = mlp(x1, m2); z2,g2 = flow(x2, theta2)
  mlp_A(x1v, m2w2, m2b2, wsf + 130, abcol, amin);
  bool hl2 = __any(amin < 1e-10f);
  float z2, ld2;
  flow_dev(x2v, abcol, hl2, z2, ld2);

  // theta1 = mlp(z2, m1); z1,g1 = flow(x1, theta1)
  mlp_A(z2, m1w2, m1b2, wsf, abcol, amin);
  bool hl1 = __any(amin < 1e-10f);
  float z1, ld1;
  flow_dev(x1v, abcol, hl1, z1, ld1);

  // z = [z2, z1]; log_dz_dx = [ld2, ld1]
  reinterpret_cast<float2*>(out)[i] = make_float2(z2, z1);
  reinterpret_cast<float2*>(out + 2 * (size_t)n)[i] = make_float2(ld2, ld1);
}

extern "C" void kernel_launch(void* const* d_in, const int* in_sizes, int n_in,
                              void* d_out, int out_size, void* d_ws, size_t ws_size,
                              hipStream_t stream) {
  const float* x    = (const float*)d_in[0];
  const float* m1w0 = (const float*)d_in[1];
  const float* m1b0 = (const float*)d_in[2];
  const float* m1w1 = (const float*)d_in[3];
  const float* m1b1 = (const float*)d_in[4];
  const float* m1w2 = (const float*)d_in[5];
  const float* m1b2 = (const float*)d_in[6];
  const float* m1w3 = (const float*)d_in[7];
  const float* m1b3 = (const float*)d_in[8];
  const float* m2w0 = (const float*)d_in[9];
  const float* m2b0 = (const float*)d_in[10];
  const float* m2w1 = (const float*)d_in[11];
  const float* m2b1 = (const float*)d_in[12];
  const float* m2w2 = (const float*)d_in[13];
  const float* m2b2 = (const float*)d_in[14];
  const float* m2w3 = (const float*)d_in[15];
  const float* m2b3 = (const float*)d_in[16];
  float* out = (float*)d_out;
  float* wsf = (float*)d_ws;
  int n = in_sizes[0] / 2;

  Basis bs;
  compute_basis_host(&bs);

  fold_kernel<<<1, THREADS, 0, stream>>>(
      m1w0, m1b0, m1w1, m1b1, m1w3, m1b3,
      m2w0, m2b0, m2w1, m2b1, m2w3, m2b3, wsf, bs);

  dim3 grid((n + THREADS - 1) / THREADS), block(THREADS);
  cpab2d_kernel<<<grid, block, 0, stream>>>(
      x, m1w2, m1b2, m2w2, m2b2, wsf, out, n);
}

// Round 13
// 42.915 us; speedup vs baseline: 1.3731x; 1.0676x over previous
//
#include <hip/hip_runtime.h>
#include <cmath>

#define THREADS 256
#define NCELL 10
#define DDIM 9

#define LN2F 0.69314718056f
#define K10L 14.426950408889634f   /* 10/ln2 */
#define LIN_THR_L 1.442695e-10f    /* 1e-10/ln2 */

typedef float f32x2 __attribute__((ext_vector_type(2)));

__device__ __forceinline__ f32x2 fma2(f32x2 a, f32x2 b, f32x2 c) {
  return __builtin_elementwise_fma(a, b, c);   // v_pk_fma_f32 on gfx950
}
__device__ __forceinline__ f32x2 max2(f32x2 a, f32x2 b) {
  return __builtin_elementwise_max(a, b);      // v_pk_max_f32
}

struct Basis { float Bt[DDIM][2 * NCELL]; }; // Bt[t][l] = B[l][t]

// Reproduce numpy.linalg.svd(L) Vt[11:] rows: LAPACK dgesdd Path 4t leaves
// rows m..n-1 of VT equal to the LQ-factorization orthogonal complement.
static void compute_basis_host(Basis* bs) {
  double L[11][20];
  for (int r = 0; r < 11; ++r)
    for (int c = 0; c < 20; ++c) L[r][c] = 0.0;
  for (int k = 1; k < NCELL; ++k) {
    double xk = (double)k / (double)NCELL;
    L[k - 1][2 * (k - 1)] = xk;
    L[k - 1][2 * (k - 1) + 1] = 1.0;
    L[k - 1][2 * k] = -xk;
    L[k - 1][2 * k + 1] = -1.0;
  }
  L[NCELL - 1][1] = 1.0;
  L[NCELL][2 * (NCELL - 1)] = 1.0;
  L[NCELL][2 * (NCELL - 1) + 1] = 1.0;

  double v[11][20];
  double tau[11];
  for (int i = 0; i < 11; ++i) {
    double alpha = L[i][i];
    double xn2 = 0.0;
    for (int l = i + 1; l < 20; ++l) xn2 += L[i][l] * L[i][l];
    double xnorm = sqrt(xn2);
    for (int l = 0; l < 20; ++l) v[i][l] = 0.0;
    v[i][i] = 1.0;
    if (xnorm == 0.0) {
      tau[i] = 0.0;
    } else {
      double beta = sqrt(alpha * alpha + xn2);
      if (alpha >= 0.0) beta = -beta;        // dlarfg: beta = -sign(alpha)*norm
      tau[i] = (beta - alpha) / beta;
      double sc = 1.0 / (alpha - beta);
      for (int l = i + 1; l < 20; ++l) v[i][l] = L[i][l] * sc;
      L[i][i] = beta;
      for (int j = i + 1; j < 11; ++j) {
        double w = 0.0;
        for (int l = i; l < 20; ++l) w += L[j][l] * v[i][l];
        w *= tau[i];
        for (int l = i; l < 20; ++l) L[j][l] -= w * v[i][l];
      }
    }
  }
  for (int j = 11; j < 20; ++j) {
    double q[20];
    for (int l = 0; l < 20; ++l) q[l] = 0.0;
    q[j] = 1.0;
    for (int i = 10; i >= 0; --i) {
      double w = 0.0;
      for (int l = i; l < 20; ++l) w += v[i][l] * q[l];
      w *= tau[i];
      for (int l = i; l < 20; ++l) q[l] -= w * v[i][l];
    }
    for (int l = 0; l < 20; ++l) bs->Bt[j - 11][l] = (float)q[l];
  }
}

// Per-MLP folds (130 floats each; m1 at ws[0], m2 at ws[130]):
//  [0:10)    W01[j]  = sum_r w0[r]*w1[r,j]       (layer0+1 fold: NO ReLU between)
//  [10:20)   B01[j]  = sum_r b0[r]*w1[r,j] + b1[j]
//  [20:120)  W3V[r][k] = sum_t w3[r,t]*VB[t][k+1], k=0..8; k=9 -> 0 (v10 pad)
//  [120:130) B3V[k]  = sum_t b3[t]*VB[t][k+1],  k=0..8; k=9 -> 0
__global__ void fold_kernel(
    const float* __restrict__ w0_1, const float* __restrict__ b0_1,
    const float* __restrict__ w1_1, const float* __restrict__ b1_1,
    const float* __restrict__ w3_1, const float* __restrict__ b3_1,
    const float* __restrict__ w0_2, const float* __restrict__ b0_2,
    const float* __restrict__ w1_2, const float* __restrict__ b1_2,
    const float* __restrict__ w3_2, const float* __restrict__ b3_2,
    float* __restrict__ ws, Basis bb) {
  for (int f = threadIdx.x; f < 260; f += THREADS) {
    int m = f / 130;
    int j = f % 130;
    const float* w0 = (m == 0) ? w0_1 : w0_2;
    const float* b0 = (m == 0) ? b0_1 : b0_2;
    const float* w1 = (m == 0) ? w1_1 : w1_2;
    const float* w3 = (m == 0) ? w3_1 : w3_2;
    const float* b3 = (m == 0) ? b3_1 : b3_2;
    const float* b1 = (m == 0) ? b1_1 : b1_2;
    float val = 0.0f;
    if (j < 10) {
      for (int r = 0; r < 10; ++r) val += w0[r] * w1[r * 10 + j];
    } else if (j < 20) {
      int jj = j - 10;
      for (int r = 0; r < 10; ++r) val += b0[r] * w1[r * 10 + jj];
      val += b1[jj];
    } else if (j < 120) {
      int jj = j - 20;
      int r = jj / 10, k = jj % 10;
      if (k < 9) {
        float g = (float)(k + 1) * 0.1f;
        for (int t = 0; t < DDIM; ++t)
          val += w3[r * DDIM + t] * (bb.Bt[t][2 * (k + 1)] * g + bb.Bt[t][2 * (k + 1) + 1]);
      }
    } else {
      int k = j - 120;
      if (k < 9) {
        float g = (float)(k + 1) * 0.1f;
        for (int t = 0; t < DDIM; ++t)
          val += b3[t] * (bb.Bt[t][2 * (k + 1)] * g + bb.Bt[t][2 * (k + 1) + 1]);
      }
    }
    ws[f] = val;
  }
}

// Folded MLP: h1 = relu(x*W01+B01); h2 = relu(h1@w2+b2); v1..v9 = h2@W3V+B3V
// (v0 = v10 = 0). Slot per cell: (aL = a/ln2, vL = v[c]); a_c = 10*(v[c+1]-v[c]).
// Outputs aminL (for lin vote) and bmin (interior grid |v| min, for tiny vote).
__device__ __forceinline__ void mlp_A(float xin,
    const float* __restrict__ w2, const float* __restrict__ b2,
    const float* __restrict__ wbf,     // 130 floats
    f32x2* abcol, float& aminL, float& bmin) {
  const f32x2* W01 = (const f32x2*)wbf;         // [0:5)
  const f32x2* B01 = W01 + 5;                   // [5:10)
  const f32x2* W3V = W01 + 10;                  // [10:60)
  const f32x2* B3V = W01 + 60;                  // [60:65)
  const f32x2* w2p = (const f32x2*)w2;
  const f32x2* b2p = (const f32x2*)b2;

  f32x2 h1[5], h2[5];
  f32x2 xx = {xin, xin};
  f32x2 zero = {0.0f, 0.0f};
#pragma unroll
  for (int p = 0; p < 5; ++p) h1[p] = max2(fma2(xx, W01[p], B01[p]), zero);

#pragma unroll
  for (int p = 0; p < 5; ++p) h2[p] = b2p[p];
#pragma unroll
  for (int r = 0; r < 10; ++r) {
    float h = h1[r >> 1][r & 1];
    f32x2 hh = {h, h};
#pragma unroll
    for (int p = 0; p < 5; ++p) h2[p] = fma2(hh, w2p[r * 5 + p], h2[p]);
  }
#pragma unroll
  for (int p = 0; p < 5; ++p) h2[p] = max2(h2[p], zero);

  f32x2 vp[5];                                   // (v1,v2)..(v9,v10=0)
#pragma unroll
  for (int p = 0; p < 5; ++p) vp[p] = B3V[p];
#pragma unroll
  for (int r = 0; r < 10; ++r) {
    float h = h2[r >> 1][r & 1];
    f32x2 hh = {h, h};
#pragma unroll
    for (int p = 0; p < 5; ++p) vp[p] = fma2(hh, W3V[r * 5 + p], vp[p]);
  }

  float v[NCELL + 1];
  v[0] = 0.0f;
#pragma unroll
  for (int k = 1; k <= NCELL; ++k) v[k] = vp[(k - 1) >> 1][(k - 1) & 1];

  float amn = 1e30f, bmn = 1e30f;
#pragma unroll
  for (int c = 0; c < NCELL; ++c) {
    float aL = (v[c + 1] - v[c]) * K10L;
    f32x2 ab; ab[0] = aL; ab[1] = v[c];
    abcol[c * THREADS] = ab;
    amn = fminf(amn, fabsf(aL));
    if (c >= 1) bmn = fminf(bmn, fabsf(v[c]));
  }
  aminL = amn;
  bmin = bmn;
}

// FAST cell-hop loop (guard-free: callers guarantee no |a|<1e-10 cell and no
// |v| below ~1e-12 at any grid boundary or at the start point).
//  - v is linear per cell: v(far) = v(entry) + a*d01 -> no b/xc rolls.
//  - slot a is pre-scaled a/ln2 so raL = rcp(aL) = ln2/a and
//    thit = log2(ratio)*raL uses the raw v_log_f32 with no ln2 multiply.
//  - ld telescoped to the terminal ENTRY: ld = log(ventry/v0) + aF*t, with
//    the final evolve's contribution added in LOG SPACE (exact), never by
//    recomputing v(z) (r12 bug: fma(a,z,b) cancels catastrophically when
//    a*t << 0 and v(z) ~ 1e-12 -> ld error O(0.1)).
__device__ __forceinline__ void flow_fast(float x0, const f32x2* abcol,
                                          int c0, float aL0, float v0,
                                          float& zo, float& ldo) {
  bool right = (v0 >= 0.0f);
  float d01L = right ? 0.1f * LN2F : -0.1f * LN2F;
  int dirI = right ? 1 : -1;
  float c0f = (float)c0;
  float xc0 = (right ? c0f + 1.0f : c0f) * 0.1f;

  float rv0 = __builtin_amdgcn_rcpf(v0);
  float rv = rv0;
  float aL = aL0;
  float raL = __builtin_amdgcn_rcpf(aL);
  float ventry = v0;
  float t = 1.0f;
  int c = c0;
  bool cross;

  // prefetch next cell's aL
  int cn = c + dirI; cn = cn < 0 ? 0 : (cn > 9 ? 9 : cn);
  float aLn = abcol[cn * THREADS][0];
  float ran = __builtin_amdgcn_rcpf(aLn);

  // peeled first step (entry at x0, not a boundary)
  {
    float dxL = (xc0 - x0) * LN2F;
    float vxc = fmaf(aL, dxL, ventry);
    float ratio = fmaxf(vxc * rv, 1e-30f);
    float thit = __log2f(ratio) * raL;
    cross = thit < t;
    t = cross ? t - thit : t;
    ventry = cross ? vxc : ventry;
    float rvn = __builtin_amdgcn_rcpf(vxc);
    rv = cross ? rvn : rv;
    aL = cross ? aLn : aL;
    raL = cross ? ran : raL;
    c = cross ? cn : c;
  }
  if (!__all(!cross)) {
    cn = c + dirI; cn = cn < 0 ? 0 : (cn > 9 ? 9 : cn);
    aLn = abcol[cn * THREADS][0];
    ran = __builtin_amdgcn_rcpf(aLn);
    for (int it = 1; it < NCELL; ++it) {
      float vxc = fmaf(aL, d01L, ventry);     // v(far) = v(entry) + a*d01
      float ratio = fmaxf(vxc * rv, 1e-30f);
      float thit = __log2f(ratio) * raL;
      cross = cross && (thit < t);            // sticky: frozen stays frozen
      t = cross ? t - thit : t;
      ventry = cross ? vxc : ventry;
      float rvn = __builtin_amdgcn_rcpf(vxc);
      rv = cross ? rvn : rv;
      aL = cross ? aLn : aL;
      raL = cross ? ran : raL;
      c = cross ? cn : c;
      if (__all(!cross)) break;
      cn = c + dirI; cn = cn < 0 ? 0 : (cn > 9 ? 9 : cn);
      aLn = abcol[cn * THREADS][0];
      ran = __builtin_amdgcn_rcpf(aLn);
    }
  }
  // epilogue: reconstruct terminal cell, evolve once; ld in log space.
  float aF = aL * LN2F;
  bool moved = t != 1.0f;
  float ceF = (float)(right ? c : c + 1) * 0.1f;  // terminal entry boundary
  float x_e = moved ? ceF : x0;
  float bF = fmaf(-aF, x_e, ventry);              // b = v(x_e) - a*x_e
  float rsa = __builtin_amdgcn_rcpf(aF);
  float bsa = bF * rsa;
  float E = __expf(aF * t);
  float z = fmaf(x_e + bsa, E, -bsa);
  bool done = !cross;         // exhausted-while-crossing: stay at boundary
  z = done ? z : x_e;
  float ld = __logf(fmaxf(ventry * rv0, 1e-30f)); // telescoped to terminal entry
  ld += done ? aF * t : 0.0f;                     // evolve factor, log-space exact
  zo = z;
  ldo = ld;
}

// SLOW fallback (r11-verbatim semantics incl. lin/tiny guards); b derived
// from (aL, vL) slots. Wave-uniform entry, essentially never taken.
__device__ __noinline__ void flow_slow(float x0, const f32x2* abcol,
                                       int c0, float aL0, float v0,
                                       float& zo, float& ldo) {
  bool right = (v0 >= 0.0f);
  float d01 = right ? 0.1f : -0.1f;
  int dirI = right ? 1 : -1;
  float a = aL0 * LN2F;
  float b = fmaf(-a, (float)c0 * 0.1f, abcol[c0 * THREADS][1]);
  float xc = (float)(right ? (c0 + 1) : c0) * 0.1f;
  float rv0 = __builtin_amdgcn_rcpf(v0);
  float rv = rv0;
  bool tiny = fabsf(v0) < 1e-14f;
  bool lin = fabsf(a) < 1e-10f;
  float ra = __builtin_amdgcn_rcpf(lin ? 1.0f : a);
  float phiC = x0;
  float t = 1.0f;
  bool cross = false;
  int c = c0;

  int cn = c + dirI; cn = cn < 0 ? 0 : (cn > 9 ? 9 : cn);
  f32x2 sn = abcol[cn * THREADS];
  float an = sn[0] * LN2F;
  float bn = fmaf(-an, (float)cn * 0.1f, sn[1]);
  bool linn = fabsf(an) < 1e-10f;
  float ran = __builtin_amdgcn_rcpf(linn ? 1.0f : an);

  for (int it = 0; it < NCELL; ++it) {
    float vxc = fmaf(a, xc, b);
    float ratio = fmaxf(vxc * rv, 1e-30f);
    float l = __logf(ratio);
    float thit = l * ra;
    if (lin) {
      float sb = (fabsf(b) < 1e-30f) ? 1.0f : b;
      thit = (xc - phiC) * __builtin_amdgcn_rcpf(sb);
    }
    thit = tiny ? __builtin_inff() : thit;
    bool crN = (thit < t);
    cross = (it == 0) ? crN : (cross && crN);
    t = cross ? (t - thit) : t;
    phiC = cross ? xc : phiC;
    float rvn = __builtin_amdgcn_rcpf(vxc);
    rv = cross ? rvn : rv;
    tiny = cross ? (fabsf(vxc) < 1e-14f) : tiny;
    a = cross ? an : a;
    b = cross ? bn : b;
    lin = cross ? linn : lin;
    ra = cross ? ran : ra;
    xc = cross ? (xc + d01) : xc;
    c = cross ? cn : c;
    if (__all(!cross)) break;
    cn = c + dirI; cn = cn < 0 ? 0 : (cn > 9 ? 9 : cn);
    sn = abcol[cn * THREADS];
    an = sn[0] * LN2F;
    bn = fmaf(-an, (float)cn * 0.1f, sn[1]);
    linn = fabsf(an) < 1e-10f;
    ran = __builtin_amdgcn_rcpf(linn ? 1.0f : an);
  }
  bool done = !cross;
  float vterm = fmaf(a, phiC, b);
  float ld = __logf(fmaxf(vterm * rv0, 1e-30f));
  bool linf = fabsf(a) < 1e-10f;
  float rsaf = __builtin_amdgcn_rcpf(linf ? 1.0f : a);
  float bsa = b * rsaf;
  float E = __expf(a * t);
  float pnl = fmaf(phiC + bsa, E, -bsa);
  float pli = fmaf(b, t, phiC);
  float p1 = linf ? pli : pnl;
  zo = done ? p1 : phiC;
  ldo = ld + (done ? a * t : 0.0f);
}

__device__ __forceinline__ void flow_dev(float x0, const f32x2* abcol,
                                         float aminL, float bmin,
                                         float& zo, float& ldo) {
  int c0 = (int)(x0 * 10.0f);
  c0 = c0 < 0 ? 0 : (c0 > 9 ? 9 : c0);
  f32x2 s0 = abcol[c0 * THREADS];
  float aL0 = s0[0], vL0 = s0[1];
  float dxL = (x0 - (float)c0 * 0.1f) * LN2F;
  float v0 = fmaf(aL0, dxL, vL0);
  bool risky = (aminL < LIN_THR_L) || (bmin < 1e-12f) || (fabsf(v0) < 1e-12f);
  if (__any(risky)) {
    flow_slow(x0, abcol, c0, aL0, v0, zo, ldo);
  } else {
    flow_fast(x0, abcol, c0, aL0, v0, zo, ldo);
  }
}

__global__ __launch_bounds__(THREADS, 4) void cpab2d_kernel(
    const float* __restrict__ x,
    const float* __restrict__ m1w2, const float* __restrict__ m1b2,
    const float* __restrict__ m2w2, const float* __restrict__ m2b2,
    const float* __restrict__ wsf,
    float* __restrict__ out, int n) {
  __shared__ f32x2 AB[NCELL][THREADS];   // (a/ln2, vL); [cell][tid]
  int i = blockIdx.x * THREADS + threadIdx.x;
  if (i >= n) return;

  float2 xi = reinterpret_cast<const float2*>(x)[i];
  // xs = x[:, [1,0]]: x1 = x[:,1], x2 = x[:,0]; both clipped first
  float x2v = fminf(fmaxf(xi.x, 1e-7f), 1.0f - 1e-7f);
  float x1v = fminf(fmaxf(xi.y, 1e-7f), 1.0f - 1e-7f);

  f32x2* abcol = &AB[0][threadIdx.x];
  float aminL, bmin;

  // theta2 = mlp(x1, m2); z2,g2 = flow(x2, theta2)
  mlp_A(x1v, m2w2, m2b2, wsf + 130, abcol, aminL, bmin);
  float z2, ld2;
  flow_dev(x2v, abcol, aminL, bmin, z2, ld2);

  // theta1 = mlp(z2, m1); z1,g1 = flow(x1, theta1)
  mlp_A(z2, m1w2, m1b2, wsf, abcol, aminL, bmin);
  float z1, ld1;
  flow_dev(x1v, abcol, aminL, bmin, z1, ld1);

  // z = [z2, z1]; log_dz_dx = [ld2, ld1]
  reinterpret_cast<float2*>(out)[i] = make_float2(z2, z1);
  reinterpret_cast<float2*>(out + 2 * (size_t)n)[i] = make_float2(ld2, ld1);
}

extern "C" void kernel_launch(void* const* d_in, const int* in_sizes, int n_in,
                              void* d_out, int out_size, void* d_ws, size_t ws_size,
                              hipStream_t stream) {
  const float* x    = (const float*)d_in[0];
  const float* m1w0 = (const float*)d_in[1];
  const float* m1b0 = (const float*)d_in[2];
  const float* m1w1 = (const float*)d_in[3];
  const float* m1b1 = (const float*)d_in[4];
  const float* m1w2 = (const float*)d_in[5];
  const float* m1b2 = (const float*)d_in[6];
  const float* m1w3 = (const float*)d_in[7];
  const float* m1b3 = (const float*)d_in[8];
  const float* m2w0 = (const float*)d_in[9];
  const float* m2b0 = (const float*)d_in[10];
  const float* m2w1 = (const float*)d_in[11];
  const float* m2b1 = (const float*)d_in[12];
  const float* m2w2 = (const float*)d_in[13];
  const float* m2b2 = (const float*)d_in[14];
  const float* m2w3 = (const float*)d_in[15];
  const float* m2b3 = (const float*)d_in[16];
  float* out = (float*)d_out;
  float* wsf = (float*)d_ws;
  int n = in_sizes[0] / 2;

  Basis bs;
  compute_basis_host(&bs);

  fold_kernel<<<1, THREADS, 0, stream>>>(
      m1w0, m1b0, m1w1, m1b1, m1w3, m1b3,
      m2w0, m2b0, m2w1, m2b1, m2w3, m2b3, wsf, bs);

  dim3 grid((n + THREADS - 1) / THREADS), block(THREADS);
  cpab2d_kernel<<<grid, block, 0, stream>>>(
      x, m1w2, m1b2, m2w2, m2b2, wsf, out, n);
}